// Round 7
// baseline (58.998 us; speedup 1.0000x reference)
//
#include <hip/hip_runtime.h>
#include <hip/hip_bf16.h>
#include <math.h>

// Problem constants (from reference)
#define BB 32
#define CC 30
#define RR 196
#define DD 256
#define KK 20
#define GG 14            // sqrt(RR)
#define CONF_ 0.5f
#define IOU_THR_ 0.3f

constexpr int COORDS_OFF = 0;                // (B,C,K,4)
constexpr int PROBS_OFF  = BB * CC * KK * 4; // 76800
constexpr int KEEP_OFF   = PROBS_OFF + BB * CC * KK;  // 96000
constexpr int PRES_OFF   = KEEP_OFF + BB * CC * KK;   // 115200

__device__ __forceinline__ float dot4(float4 a, float4 b) {
    return a.x * b.x + a.y * b.y + a.z * b.z + a.w * b.w;
}

// ---------------------------------------------------------------------------
// ONE kernel, one block per (b,c) tile, 960 blocks x 256 threads.
// Phase 1 (R6 restructure — memory-level parallelism):
//   32 lanes/row, 2 taps/lane (weights = 10 float4 = 40 VGPR).
//   Granule g = row pair {base+2g, base+2g+1}: lanes 0-31 -> even row,
//   lanes 32-63 -> odd row; 2 load instructions = 2 KiB.
//   4-buffer software pipeline (A,B,C,D): compute a granule, then
//   immediately issue its replacement loads -> ~3 granules (6 KiB/wave)
//   outstanding through every compute window, ~96 KiB/CU at 16 waves/CU.
//   (R5 lesson: the 4KiB-issue-then-drain body averaged far less in flight
//   -> Little's law capped the stream at ~3.9 TB/s.)
// Phase 2: wave 0 epilogue from LDS (unchanged from R5, passing).
// ---------------------------------------------------------------------------
__global__ __launch_bounds__(256, 4) void fused_bbox_deep(
    const float4* __restrict__ lf,        // (B*C*R) x 64 float4
    const float*  __restrict__ W_coords,  // 4 x 256
    const float*  __restrict__ b_coords,  // 4
    const float*  __restrict__ W_pres,    // 256
    const float*  __restrict__ b_pres,    // 1
    float* __restrict__ coords_out,
    float* __restrict__ probs_out,
    float* __restrict__ keep_out,
    float* __restrict__ presence_out)
{
    const int bc   = blockIdx.x;
    const int tid  = threadIdx.x;
    const int wv   = tid >> 6;
    const int lane = tid & 63;
    const int o2   = lane & 31;   // float4 slot within row half (2 taps: o2, o2+32)
    const int hr   = lane >> 5;   // 0: even row of pair, 1: odd row

    __shared__ float  s_logit[RR];
    __shared__ float4 s_box[RR];

    const float4* __restrict__ Wp4 = reinterpret_cast<const float4*>(W_pres);
    const float4* __restrict__ Wc4 = reinterpret_cast<const float4*>(W_coords);

    // Weights pinned in registers: 10 float4 = 40 VGPR.
    const float4 wp0 = Wp4[o2],        wp1 = Wp4[o2 + 32];
    const float4 wa0 = Wc4[o2],        wa1 = Wc4[o2 + 32];
    const float4 wb0 = Wc4[64 + o2],   wb1 = Wc4[96 + o2];
    const float4 wc0 = Wc4[128 + o2],  wc1 = Wc4[160 + o2];
    const float4 wd0 = Wc4[192 + o2],  wd1 = Wc4[224 + o2];

    const float bp  = b_pres[0];
    const float bc0 = b_coords[0], bc1 = b_coords[1];
    const float bc2 = b_coords[2], bc3 = b_coords[3];

    const size_t tileRows = (size_t)bc * RR;
    const float4* __restrict__ tp = lf + tileRows * 64;
    const int base = wv * 49;     // 4 waves x 49 rows = 196

#define LOADG(X0, X1, g)                                                 \
    {                                                                    \
        const float4* __restrict__ _p = tp + (size_t)(base + 2*(g) + hr) * 64; \
        X0 = _p[o2];                                                     \
        X1 = _p[o2 + 32];                                                \
    }

#define COMPG(g, X0, X1)                                                 \
    {                                                                    \
        float ap = dot4(X0, wp0) + dot4(X1, wp1);                        \
        float a0 = dot4(X0, wa0) + dot4(X1, wa1);                        \
        float a1 = dot4(X0, wb0) + dot4(X1, wb1);                        \
        float a2 = dot4(X0, wc0) + dot4(X1, wc1);                        \
        float a3 = dot4(X0, wd0) + dot4(X1, wd1);                        \
        _Pragma("unroll")                                                \
        for (int off = 1; off <= 16; off <<= 1) {                        \
            ap += __shfl_xor(ap, off);                                   \
            a0 += __shfl_xor(a0, off);                                   \
            a1 += __shfl_xor(a1, off);                                   \
            a2 += __shfl_xor(a2, off);                                   \
            a3 += __shfl_xor(a3, off);                                   \
        }                                                                \
        if (o2 == 0) {                                                   \
            const int r = base + 2*(g) + hr;                             \
            const float lg = ap + bp;                                    \
            s_logit[r] = lg;                                             \
            presence_out[tileRows + r] = lg;                             \
            const int   ix = r % GG, iy = r / GG;                        \
            const float cx = (ix + 0.5f) / (float)GG;                    \
            const float cy = (iy + 0.5f) / (float)GG;                    \
            s_box[r] = make_float4(a0 + bc0 + cx, a1 + bc1 + cy,         \
                                   a2 + bc2 + cx, a3 + bc3 + cy);        \
        }                                                                \
    }

    // ---- tail row (base+48) loads issued first (oldest in flight) ----
    float4 t0, t1;
    {
        const float4* __restrict__ _p = tp + (size_t)(base + 48) * 64;
        t0 = _p[o2];
        t1 = _p[o2 + 32];
    }

    // ---- pipeline prologue: 4 granules (8 loads, 8 KiB) in flight ----
    float4 A0, A1, B0, B1, C0, C1, D0, D1;
    LOADG(A0, A1, 0)
    LOADG(B0, B1, 1)
    LOADG(C0, C1, 2)
    LOADG(D0, D1, 3)

    // ---- main loop: 24 granules, compute-then-refill per buffer ----
    #pragma unroll 1
    for (int it = 0; it < 24; it += 4) {
        COMPG(it,     A0, A1)
        if (it + 4 < 24) LOADG(A0, A1, it + 4)
        COMPG(it + 1, B0, B1)
        if (it + 5 < 24) LOADG(B0, B1, it + 5)
        COMPG(it + 2, C0, C1)
        if (it + 6 < 24) LOADG(C0, C1, it + 6)
        COMPG(it + 3, D0, D1)
        if (it + 7 < 24) LOADG(D0, D1, it + 7)
    }

    // ---- tail row: both halves compute it redundantly; lane 0 writes ----
    {
        float ap = dot4(t0, wp0) + dot4(t1, wp1);
        float a0 = dot4(t0, wa0) + dot4(t1, wa1);
        float a1 = dot4(t0, wb0) + dot4(t1, wb1);
        float a2 = dot4(t0, wc0) + dot4(t1, wc1);
        float a3 = dot4(t0, wd0) + dot4(t1, wd1);
        #pragma unroll
        for (int off = 1; off <= 16; off <<= 1) {
            ap += __shfl_xor(ap, off);
            a0 += __shfl_xor(a0, off);
            a1 += __shfl_xor(a1, off);
            a2 += __shfl_xor(a2, off);
            a3 += __shfl_xor(a3, off);
        }
        if (lane == 0) {
            const int r = base + 48;
            const float lg = ap + bp;
            s_logit[r] = lg;
            presence_out[tileRows + r] = lg;
            const int   ix = r % GG, iy = r / GG;
            const float cx = (ix + 0.5f) / (float)GG;
            const float cy = (iy + 0.5f) / (float)GG;
            s_box[r] = make_float4(a0 + bc0 + cx, a1 + bc1 + cy,
                                   a2 + bc2 + cx, a3 + bc3 + cy);
        }
    }

    __syncthreads();
    if (wv != 0) return;

    // ---- Phase 2 (wave 0): top-K argmax over LDS logits ----
    float v[4]; int id[4];
    #pragma unroll
    for (int t = 0; t < 4; ++t) {
        const int r = lane + 64 * t;
        id[t] = r;
        v[t]  = (r < RR) ? s_logit[r] : -1e30f;
    }

    float myv = -1e30f; int myi = 0;
    for (int k = 0; k < KK; ++k) {
        float bv = v[0]; int bi = id[0];
        #pragma unroll
        for (int t = 1; t < 4; ++t)
            if (v[t] > bv || (v[t] == bv && id[t] < bi)) { bv = v[t]; bi = id[t]; }
        #pragma unroll
        for (int off = 32; off; off >>= 1) {
            const float ov = __shfl_xor(bv, off);
            const int   oi = __shfl_xor(bi, off);
            if (ov > bv || (ov == bv && oi < bi)) { bv = ov; bi = oi; }
        }
        #pragma unroll
        for (int t = 0; t < 4; ++t)
            if (id[t] == bi) v[t] = -1e30f;
        if (lane == k) { myv = bv; myi = bi; }
    }

    // ---- box fetch + NMS ----
    float x1 = 0.f, y1 = 0.f, x2 = 0.f, y2 = 0.f, area = 0.f, prob = 0.f;
    int kp = 0;
    if (lane < KK) {
        const float4 b = s_box[myi];
        x1 = b.x; y1 = b.y; x2 = b.z; y2 = b.w;
        area = fmaxf(x2 - x1, 0.f) * fmaxf(y2 - y1, 0.f);
        prob = 1.f / (1.f + expf(-myv));
        kp   = (prob > CONF_) ? 1 : 0;
    }
    for (int i = 0; i < KK; ++i) {
        const int   ki  = __shfl(kp, i);
        const float bx1 = __shfl(x1, i), by1 = __shfl(y1, i);
        const float bx2 = __shfl(x2, i), by2 = __shfl(y2, i);
        const float ai  = __shfl(area, i);
        if (lane > i && lane < KK && ki) {
            const float xx1 = fmaxf(x1, bx1), yy1 = fmaxf(y1, by1);
            const float xx2 = fminf(x2, bx2), yy2 = fminf(y2, by2);
            const float inter = fmaxf(xx2 - xx1, 0.f) * fmaxf(yy2 - yy1, 0.f);
            const float uni   = area + ai - inter;
            const float iou   = inter / fmaxf(uni, 1e-9f);
            if (iou > IOU_THR_) kp = 0;
        }
    }

    // ---- outputs ----
    if (lane < KK) {
        const size_t obase = (size_t)bc * KK + lane;
        const float  kf    = kp ? 1.f : 0.f;
        coords_out[obase * 4 + 0] = x1 * kf;
        coords_out[obase * 4 + 1] = y1 * kf;
        coords_out[obase * 4 + 2] = x2 * kf;
        coords_out[obase * 4 + 3] = y2 * kf;
        probs_out[obase] = prob * kf;
        keep_out[obase]  = kf;
    }
#undef LOADG
#undef COMPG
}

extern "C" void kernel_launch(void* const* d_in, const int* in_sizes, int n_in,
                              void* d_out, int out_size, void* d_ws, size_t ws_size,
                              hipStream_t stream) {
    const float* lf       = (const float*)d_in[0];
    const float* W_coords = (const float*)d_in[1];
    const float* b_coords = (const float*)d_in[2];
    const float* W_pres   = (const float*)d_in[3];
    const float* b_pres   = (const float*)d_in[4];

    float* out          = (float*)d_out;
    float* coords_out   = out + COORDS_OFF;
    float* probs_out    = out + PROBS_OFF;
    float* keep_out     = out + KEEP_OFF;
    float* presence_out = out + PRES_OFF;

    // One block per (b,c); 960 blocks, fully independent (single launch).
    fused_bbox_deep<<<BB * CC, 256, 0, stream>>>(
        (const float4*)lf, W_coords, b_coords, W_pres, b_pres,
        coords_out, probs_out, keep_out, presence_out);
}